// Round 5
// baseline (112.606 us; speedup 1.0000x reference)
//
#include <hip/hip_runtime.h>

// Problem constants: x (8, 8192, 512) f32, W (512,128) f32, perm (128,) f32
#define B_ 8
#define N_ 8192
#define D_ 512
#define R_ 128
#define CHUNKS_ 64             // chunks per batch; grid = B_*CHUNKS_ = 512
#define ROWS_ 128              // N_/CHUNKS_
#define GRID_ (B_ * CHUNKS_)   // 512 blocks

// Single fused kernel with a manual grid barrier (atomic counter + fences).
// 512 blocks x 512 threads = 2 blocks/CU — co-residency margin is large
// (LDS 12.5KB/block allows 12/CU; 16/32 waves/CU), so the spin barrier
// cannot deadlock in practice.
__global__ __launch_bounds__(512) void k_fused(const float* __restrict__ x,
                                               const float* __restrict__ W,
                                               const float* __restrict__ perm,
                                               float* __restrict__ partial_y,
                                               unsigned int* __restrict__ counter,
                                               float* __restrict__ out) {
    const int b  = blockIdx.x >> 6;         // / CHUNKS_
    const int ck = blockIdx.x & (CHUNKS_ - 1);
    const int t  = threadIdx.x;

    __shared__ float4 s4[512];
    __shared__ float  xs[D_];
    __shared__ float  red[512];
    __shared__ float  yv[R_];

    // ---- Phase 1: stream ROWS_ rows, column-sum into xs ----
    const int dq = t & 127;                 // float4 column over d
    const int rp = t >> 7;                  // 0..3 row-parallel groups
    const float4* x4 = reinterpret_cast<const float4*>(x)
                       + ((size_t)b * N_ + (size_t)ck * ROWS_) * (D_ / 4);

    float4 acc = make_float4(0.f, 0.f, 0.f, 0.f);
    #pragma unroll 8
    for (int n = rp; n < ROWS_; n += 4) {
        float4 v = x4[(size_t)n * (D_ / 4) + dq];
        acc.x += v.x; acc.y += v.y; acc.z += v.z; acc.w += v.w;
    }
    s4[t] = acc;
    __syncthreads();
    if (rp == 0) {
        float4 a1 = s4[dq + 128], a2 = s4[dq + 256], a3 = s4[dq + 384];
        float4 r;
        r.x = (acc.x + a1.x) + (a2.x + a3.x);
        r.y = (acc.y + a1.y) + (a2.y + a3.y);
        r.z = (acc.z + a1.z) + (a2.z + a3.z);
        r.w = (acc.w + a1.w) + (a2.w + a3.w);
        reinterpret_cast<float4*>(xs)[dq] = r;
    }
    __syncthreads();

    // ---- project chunk sum through W: 4 groups x 128 channels ----
    const int r = t & 127;
    const int g = t >> 7;                   // 0..3, covers d = g*128 .. +127
    float a = 0.f;
    #pragma unroll 8
    for (int d0 = 0; d0 < 128; ++d0) {
        const int d = g * 128 + d0;
        a = fmaf(xs[d], W[(size_t)d * R_ + r], a);
    }
    red[t] = a;
    __syncthreads();
    if (g == 0) {
        float v = (red[r] + red[r + 128]) + (red[r + 256] + red[r + 384]);
        partial_y[(size_t)blockIdx.x * R_ + r] = v;
    }
    __syncthreads();

    // ---- Manual grid barrier ----
    if (t == 0) {
        __threadfence();                    // release partial_y device-wide
        atomicAdd(counter, 1u);
        while (__hip_atomic_load(counter, __ATOMIC_ACQUIRE,
                                 __HIP_MEMORY_SCOPE_AGENT) < (unsigned)GRID_) {
            __builtin_amdgcn_s_sleep(8);
        }
        __threadfence();                    // acquire: drop stale cached lines
    }
    __syncthreads();

    // ---- Phase 2: sum chunk projections for b, scale, broadcast-write ----
    const int q4 = t >> 7;                  // 0..3 over chunk quarters
    const float* p = partial_y
                     + ((size_t)b * CHUNKS_ + (size_t)q4 * (CHUNKS_ / 4)) * R_ + r;
    float s = 0.f;
    #pragma unroll 8
    for (int c = 0; c < CHUNKS_ / 4; ++c)
        s += p[(size_t)c * R_];
    red[t] = s;
    __syncthreads();
    if (q4 == 0)
        yv[r] = ((red[r] + red[r + 128]) + (red[r + 256] + red[r + 384]))
                * perm[r] * (1.0f / (float)N_);
    __syncthreads();

    const int q   = t & 31;                 // float4 column 0..31
    const int rp2 = t >> 5;                 // 0..15
    const float4 val = reinterpret_cast<const float4*>(yv)[q];
    float4* out4 = reinterpret_cast<float4*>(out)
                   + ((size_t)b * N_ + (size_t)ck * ROWS_) * (R_ / 4);
    #pragma unroll
    for (int n = rp2; n < ROWS_; n += 16)
        out4[(size_t)n * (R_ / 4) + q] = val;
}

extern "C" void kernel_launch(void* const* d_in, const int* in_sizes, int n_in,
                              void* d_out, int out_size, void* d_ws, size_t ws_size,
                              hipStream_t stream) {
    const float* x    = (const float*)d_in[0];
    const float* W    = (const float*)d_in[1];
    const float* perm = (const float*)d_in[2];
    float* out = (float*)d_out;

    unsigned int* counter = (unsigned int*)d_ws;                 // 4 B (reset below)
    float* partial_y = (float*)((char*)d_ws + 256);              // 256 KB

    hipMemsetAsync(counter, 0, sizeof(unsigned int), stream);
    k_fused<<<dim3(GRID_), dim3(512), 0, stream>>>(x, W, perm, partial_y, counter, out);
}

// Round 6
// 81.108 us; speedup vs baseline: 1.3884x; 1.3884x over previous
//
#include <hip/hip_runtime.h>

// Problem constants: x (8, 8192, 512) f32, W (512,128) f32, perm (128,) f32
#define B_ 8
#define N_ 8192
#define D_ 512
#define R_ 128
#define CHUNKS_ 64             // chunks per batch; grid = B_*CHUNKS_ = 512
#define ROWS_ 128              // N_/CHUNKS_
#define GRID_ (B_ * CHUNKS_)   // 512 blocks

// Single fused kernel with a manual grid barrier.
// Barrier discipline (the R4 lesson): ONE release-atomicAdd, RELAXED spin
// (no per-iteration cache invalidates), ONE acquire load on exit. The
// leader's acquire invalidates the CU's L1, which the whole block shares;
// __syncthreads() then orders the block behind it.
__global__ __launch_bounds__(512) void k_fused(const float* __restrict__ x,
                                               const float* __restrict__ W,
                                               const float* __restrict__ perm,
                                               float* __restrict__ partial_y,
                                               unsigned int* __restrict__ counter,
                                               float* __restrict__ out) {
    const int b  = blockIdx.x >> 6;         // / CHUNKS_
    const int ck = blockIdx.x & (CHUNKS_ - 1);
    const int t  = threadIdx.x;

    __shared__ float4 s4[512];
    __shared__ float  xs[D_];
    __shared__ float  red[512];
    __shared__ float  yv[R_];

    // ---- Phase 1: stream ROWS_ rows, column-sum into xs ----
    const int dq = t & 127;                 // float4 column over d
    const int rp = t >> 7;                  // 0..3 row-parallel groups
    const float4* x4 = reinterpret_cast<const float4*>(x)
                       + ((size_t)b * N_ + (size_t)ck * ROWS_) * (D_ / 4);

    float4 acc = make_float4(0.f, 0.f, 0.f, 0.f);
    #pragma unroll 8
    for (int n = rp; n < ROWS_; n += 4) {
        float4 v = x4[(size_t)n * (D_ / 4) + dq];
        acc.x += v.x; acc.y += v.y; acc.z += v.z; acc.w += v.w;
    }
    s4[t] = acc;
    __syncthreads();
    if (rp == 0) {
        float4 a1 = s4[dq + 128], a2 = s4[dq + 256], a3 = s4[dq + 384];
        float4 r;
        r.x = (acc.x + a1.x) + (a2.x + a3.x);
        r.y = (acc.y + a1.y) + (a2.y + a3.y);
        r.z = (acc.z + a1.z) + (a2.z + a3.z);
        r.w = (acc.w + a1.w) + (a2.w + a3.w);
        reinterpret_cast<float4*>(xs)[dq] = r;
    }
    __syncthreads();

    // ---- project chunk sum through W: 4 groups x 128 channels ----
    const int r = t & 127;
    const int g = t >> 7;                   // 0..3, covers d = g*128 .. +127
    float a = 0.f;
    #pragma unroll 8
    for (int d0 = 0; d0 < 128; ++d0) {
        const int d = g * 128 + d0;
        a = fmaf(xs[d], W[(size_t)d * R_ + r], a);
    }
    red[t] = a;
    __syncthreads();
    if (g == 0) {
        float v = (red[r] + red[r + 128]) + (red[r + 256] + red[r + 384]);
        partial_y[(size_t)blockIdx.x * R_ + r] = v;
    }
    __syncthreads();

    // ---- Manual grid barrier (release add / relaxed spin / one acquire) ----
    if (t == 0) {
        __hip_atomic_fetch_add(counter, 1u, __ATOMIC_RELEASE,
                               __HIP_MEMORY_SCOPE_AGENT);
        while (__hip_atomic_load(counter, __ATOMIC_RELAXED,
                                 __HIP_MEMORY_SCOPE_AGENT) < (unsigned)GRID_) {
            __builtin_amdgcn_s_sleep(2);
        }
        (void)__hip_atomic_load(counter, __ATOMIC_ACQUIRE,
                                __HIP_MEMORY_SCOPE_AGENT);
    }
    __syncthreads();

    // ---- Phase 2: sum chunk projections for b, scale, broadcast-write ----
    const int q4 = t >> 7;                  // 0..3 over chunk quarters
    const float* p = partial_y
                     + ((size_t)b * CHUNKS_ + (size_t)q4 * (CHUNKS_ / 4)) * R_ + r;
    float s = 0.f;
    #pragma unroll 8
    for (int c = 0; c < CHUNKS_ / 4; ++c)
        s += p[(size_t)c * R_];
    red[t] = s;
    __syncthreads();
    if (q4 == 0)
        yv[r] = ((red[r] + red[r + 128]) + (red[r + 256] + red[r + 384]))
                * perm[r] * (1.0f / (float)N_);
    __syncthreads();

    const int q   = t & 31;                 // float4 column 0..31
    const int rp2 = t >> 5;                 // 0..15
    const float4 val = reinterpret_cast<const float4*>(yv)[q];
    float4* out4 = reinterpret_cast<float4*>(out)
                   + ((size_t)b * N_ + (size_t)ck * ROWS_) * (R_ / 4);
    #pragma unroll
    for (int n = rp2; n < ROWS_; n += 16)
        out4[(size_t)n * (R_ / 4) + q] = val;
}

extern "C" void kernel_launch(void* const* d_in, const int* in_sizes, int n_in,
                              void* d_out, int out_size, void* d_ws, size_t ws_size,
                              hipStream_t stream) {
    const float* x    = (const float*)d_in[0];
    const float* W    = (const float*)d_in[1];
    const float* perm = (const float*)d_in[2];
    float* out = (float*)d_out;

    unsigned int* counter = (unsigned int*)d_ws;                 // 4 B (reset below)
    float* partial_y = (float*)((char*)d_ws + 256);              // 256 KB

    hipMemsetAsync(counter, 0, sizeof(unsigned int), stream);
    k_fused<<<dim3(GRID_), dim3(512), 0, stream>>>(x, W, perm, partial_y, counter, out);
}

// Round 8
// 39.060 us; speedup vs baseline: 2.8829x; 2.0765x over previous
//
#include <hip/hip_runtime.h>

// Problem constants: x (8, 8192, 512) f32, W (512,128) f32, perm (128,) f32
#define B_ 8
#define N_ 8192
#define D_ 512
#define R_ 128
#define CHUNKS_ 64             // chunks per batch; k1 grid = B_*CHUNKS_ = 512
#define ROWS_ 128              // N_/CHUNKS_

typedef float f4_t __attribute__((ext_vector_type(4)));  // native vec for nontemporal

// Kernel 1: per-chunk column-sum of x over seq axis, then project the chunk
// sum through W in-block (W is L2-resident). Emits partial_y[b][chunk][R_].
// grid = 512 blocks x 512 threads (2 blocks/CU, 16 waves/CU).
__global__ __launch_bounds__(512) void k_reduce_proj(const float* __restrict__ x,
                                                     const float* __restrict__ W,
                                                     float* __restrict__ partial_y) {
    const int b     = blockIdx.x >> 6;          // / CHUNKS_
    const int chunk = blockIdx.x & (CHUNKS_ - 1);
    const int t  = threadIdx.x;
    const int dq = t & 127;                     // float4 column over d
    const int rp = t >> 7;                      // row-parallel group 0..3

    const float4* x4 = reinterpret_cast<const float4*>(x)
                       + ((size_t)b * N_ + (size_t)chunk * ROWS_) * (D_ / 4);

    float4 acc = make_float4(0.f, 0.f, 0.f, 0.f);
    #pragma unroll 8
    for (int n = rp; n < ROWS_; n += 4) {
        float4 v = x4[(size_t)n * (D_ / 4) + dq];
        acc.x += v.x; acc.y += v.y; acc.z += v.z; acc.w += v.w;
    }

    __shared__ float4 s4[512];
    __shared__ float  xs[D_];
    __shared__ float  red[512];

    s4[t] = acc;
    __syncthreads();
    if (rp == 0) {
        float4 a1 = s4[dq + 128], a2 = s4[dq + 256], a3 = s4[dq + 384];
        float4 r;
        r.x = (acc.x + a1.x) + (a2.x + a3.x);
        r.y = (acc.y + a1.y) + (a2.y + a3.y);
        r.z = (acc.z + a1.z) + (a2.z + a3.z);
        r.w = (acc.w + a1.w) + (a2.w + a3.w);
        reinterpret_cast<float4*>(xs)[dq] = r;
    }
    __syncthreads();

    // Project: 4 groups x 128 channels; group g covers d = g*128 .. +127.
    const int r = t & 127;
    const int g = t >> 7;
    float a = 0.f;
    #pragma unroll 8
    for (int d0 = 0; d0 < 128; ++d0) {
        const int d = g * 128 + d0;
        a = fmaf(xs[d], W[(size_t)d * R_ + r], a);
    }
    red[t] = a;
    __syncthreads();
    if (g == 0) {
        float v = (red[r] + red[r + 128]) + (red[r + 256] + red[r + 384]);
        partial_y[(size_t)blockIdx.x * R_ + r] = v;
    }
}

// Kernel 2: sum the chunk projections (L2-resident, 32 KB per b), scale by
// perm/N, broadcast-write 32 output rows per block with NONTEMPORAL stores
// (out is write-once; keep it out of L3 so x stays resident for the next
// replay). grid = B_*(N_/32) = 2048 blocks x 256 threads (8/CU).
__global__ __launch_bounds__(256) void k_sumbcast(const float* __restrict__ partial_y,
                                                  const float* __restrict__ perm,
                                                  float* __restrict__ out) {
    const int b  = blockIdx.x >> 8;             // / 256 row-blocks
    const int rb = blockIdx.x & 255;
    const int t  = threadIdx.x;
    const int r    = t & 127;
    const int half = t >> 7;                    // 0..1 over chunk halves

    __shared__ float red[256];
    __shared__ float yv[R_];

    const float* p = partial_y
                     + ((size_t)b * CHUNKS_ + (size_t)half * (CHUNKS_ / 2)) * R_ + r;
    float s = 0.f;
    #pragma unroll 8
    for (int c = 0; c < CHUNKS_ / 2; ++c)
        s += p[(size_t)c * R_];
    red[t] = s;
    __syncthreads();
    if (half == 0)
        yv[r] = (red[r] + red[r + 128]) * perm[r] * (1.0f / (float)N_);
    __syncthreads();

    const int q  = t & 31;                      // float4 column 0..31
    const int rp = t >> 5;                      // 0..7
    f4_t val;
    {
        float4 v = reinterpret_cast<const float4*>(yv)[q];
        val.x = v.x; val.y = v.y; val.z = v.z; val.w = v.w;
    }
    f4_t* out4 = reinterpret_cast<f4_t*>(out)
                 + ((size_t)b * N_ + (size_t)rb * 32) * (R_ / 4);
    #pragma unroll
    for (int n = rp; n < 32; n += 8)
        __builtin_nontemporal_store(val, &out4[(size_t)n * (R_ / 4) + q]);
}

extern "C" void kernel_launch(void* const* d_in, const int* in_sizes, int n_in,
                              void* d_out, int out_size, void* d_ws, size_t ws_size,
                              hipStream_t stream) {
    const float* x    = (const float*)d_in[0];
    const float* W    = (const float*)d_in[1];
    const float* perm = (const float*)d_in[2];
    float* out = (float*)d_out;
    float* partial_y = (float*)d_ws;            // 512*128*4 = 256 KB

    k_reduce_proj<<<dim3(B_ * CHUNKS_), dim3(512), 0, stream>>>(x, W, partial_y);
    k_sumbcast  <<<dim3(B_ * (N_ / 32)), dim3(256), 0, stream>>>(partial_y, perm, out);
}